// Round 1
// baseline (1448.878 us; speedup 1.0000x reference)
//
#include <hip/hip_runtime.h>

// Problem constants: B=4096, N=32, C=512, H=16, D=32, W=32
#define SCALE_F 0.17677669529663689f  // 32^-0.5

typedef unsigned short u16;
typedef u16  u16x4 __attribute__((ext_vector_type(4)));
typedef short s16x8 __attribute__((ext_vector_type(8)));
typedef float f32x4 __attribute__((ext_vector_type(4)));

#define MFMA(a, b, c) __builtin_amdgcn_mfma_f32_16x16x32_bf16((a), (b), (c), 0, 0, 0)

static __device__ __forceinline__ u16 f2bf(float f) {
  union { float f; unsigned u; } v; v.f = f;
  unsigned r = v.u + 0x7fffu + ((v.u >> 16) & 1u);  // RNE
  return (u16)(r >> 16);
}

// ---- LDS geometry (u16 units) ----
// xbuf  : 32x512 bf16, xor-swizzled        -> 16384
// abuf  : 32x512 bf16 (att output staging) -> 16384
// rpbs  : 63x16 f32                        -> 2016 u16
// per-wave: qb/kb/vtb each 32x40 bf16 (80B rows: 16B-aligned + conflict-free)
#define AB_OFF    16384
#define RPB_OFF   32768
#define WAVE_OFF  (32768 + 2016)
#define WBUF_U16  (3 * 1280)
#define SMEM_BYTES ((WAVE_OFF + 8 * WBUF_U16) * 2)  // 131008 B

__global__ __launch_bounds__(256) void cvt_kernel(const float* __restrict__ qkv_w,
                                                  const float* __restrict__ out_w,
                                                  u16* __restrict__ wq,
                                                  u16* __restrict__ wo) {
  int i = blockIdx.x * 256 + threadIdx.x;  // 4096*256 = 1048576 = 786432 + 262144
  if (i < 786432) wq[i] = f2bf(qkv_w[i]);
  else            wo[i - 786432] = f2bf(out_w[i - 786432]);
}

__global__ __launch_bounds__(512) void swa_fused(
    const float* __restrict__ x, const u16* __restrict__ wqkv,
    const u16* __restrict__ wout, const float* __restrict__ outb,
    const float* __restrict__ rpb, float* __restrict__ out) {
  extern __shared__ u16 smem[];
  u16* xbuf = smem;
  u16* abuf = smem + AB_OFF;
  float* rpbs = (float*)(smem + RPB_OFF);
  const int tid = threadIdx.x;
  const int lane = tid & 63, wv = tid >> 6;
  const int l15 = lane & 15, g = lane >> 4;
  const long bb = blockIdx.x;
  u16* qb  = smem + WAVE_OFF + wv * WBUF_U16;  // q[n][d]; later reused for att[i][j]
  u16* kb  = qb + 1280;                        // k[j][d]
  u16* vtb = qb + 2560;                        // vT[d][y]

  // ---- stage x[b] -> bf16 swizzled LDS ----
  const f32x4* xg = (const f32x4*)(x + bb * 16384);
#pragma unroll
  for (int it = 0; it < 8; ++it) {
    int f4 = tid + it * 512;
    f32x4 v = xg[f4];
    int r = f4 >> 7, c8 = (f4 & 127) << 3;
    u16x4 p = { f2bf(v.x), f2bf(v.y), f2bf(v.z), f2bf(v.w) };
    *(u16x4*)((char*)xbuf + (((r << 10) + c8) ^ ((r & 7) << 4))) = p;
  }
  if (tid < 504) { rpbs[tid] = rpb[tid]; rpbs[tid + 504] = rpb[tid + 504]; }
  __syncthreads();

  const int r0 = l15, r1 = 16 + l15;
  const f32x4 z4 = {0.f, 0.f, 0.f, 0.f};

  for (int hh = 0; hh < 2; ++hh) {
    const int h = wv * 2 + hh;

    // ---- QKV GEMM for head h: 12 interleaved acc chains ----
    f32x4 acc[3][2][2];
#pragma unroll
    for (int m = 0; m < 3; ++m)
#pragma unroll
      for (int nt = 0; nt < 2; ++nt)
#pragma unroll
        for (int mt = 0; mt < 2; ++mt) acc[m][nt][mt] = z4;

    const char* wrow[3][2];
#pragma unroll
    for (int m = 0; m < 3; ++m)
#pragma unroll
      for (int nt = 0; nt < 2; ++nt)
        wrow[m][nt] = (const char*)wqkv +
            (((size_t)(m * 512 + h * 32 + nt * 16 + l15)) << 10) + (g << 4);

#pragma unroll
    for (int ks = 0; ks < 16; ++ks) {
      s16x8 a0 = *(const s16x8*)((const char*)xbuf +
                  (((r0 << 10) + (ks << 6) + (g << 4)) ^ ((r0 & 7) << 4)));
      s16x8 a1 = *(const s16x8*)((const char*)xbuf +
                  (((r1 << 10) + (ks << 6) + (g << 4)) ^ ((r1 & 7) << 4)));
#pragma unroll
      for (int m = 0; m < 3; ++m)
#pragma unroll
        for (int nt = 0; nt < 2; ++nt) {
          s16x8 bf = *(const s16x8*)(wrow[m][nt] + (ks << 6));
          acc[m][nt][0] = MFMA(a0, bf, acc[m][nt][0]);
          acc[m][nt][1] = MFMA(a1, bf, acc[m][nt][1]);
        }
    }

    // epilogue: q,k as [n][d] (column b16 writes); v transposed packed vT[d][y]
#pragma unroll
    for (int nt = 0; nt < 2; ++nt) {
#pragma unroll
      for (int reg = 0; reg < 4; ++reg) {
        qb[(g * 4 + reg) * 40 + nt * 16 + l15]        = f2bf(acc[0][nt][0][reg]);
        qb[(16 + g * 4 + reg) * 40 + nt * 16 + l15]   = f2bf(acc[0][nt][1][reg]);
        kb[(g * 4 + reg) * 40 + nt * 16 + l15]        = f2bf(acc[1][nt][0][reg]);
        kb[(16 + g * 4 + reg) * 40 + nt * 16 + l15]   = f2bf(acc[1][nt][1][reg]);
      }
      u16x4 p0 = { f2bf(acc[2][nt][0][0]), f2bf(acc[2][nt][0][1]),
                   f2bf(acc[2][nt][0][2]), f2bf(acc[2][nt][0][3]) };
      u16x4 p1 = { f2bf(acc[2][nt][1][0]), f2bf(acc[2][nt][1][1]),
                   f2bf(acc[2][nt][1][2]), f2bf(acc[2][nt][1][3]) };
      *(u16x4*)(vtb + (nt * 16 + l15) * 40 + g * 4) = p0;
      *(u16x4*)(vtb + (nt * 16 + l15) * 40 + 16 + g * 4) = p1;
    }
    asm volatile("s_waitcnt lgkmcnt(0)" ::: "memory");  // cross-lane LDS visibility
    __builtin_amdgcn_sched_barrier(0);

    // ---- S' = K @ Q^T : sc[nt][mt][reg] = S[j=mt*16+g*4+reg][i=nt*16+l15] ----
    f32x4 sc[2][2];
    {
      s16x8 ka0 = *(const s16x8*)((const char*)kb + l15 * 80 + (g << 4));
      s16x8 ka1 = *(const s16x8*)((const char*)kb + (16 + l15) * 80 + (g << 4));
      s16x8 qf0 = *(const s16x8*)((const char*)qb + l15 * 80 + (g << 4));
      s16x8 qf1 = *(const s16x8*)((const char*)qb + (16 + l15) * 80 + (g << 4));
      sc[0][0] = MFMA(ka0, qf0, z4);
      sc[0][1] = MFMA(ka1, qf0, z4);
      sc[1][0] = MFMA(ka0, qf1, z4);
      sc[1][1] = MFMA(ka1, qf1, z4);
    }

    // ---- double softmax over j (per column i; fp32) ----
    float att2[2][2][4];
#pragma unroll
    for (int nt = 0; nt < 2; ++nt) {
      const int i_idx = nt * 16 + l15;
      float e[2][4];
      float mx = -3.4e38f;
#pragma unroll
      for (int mt = 0; mt < 2; ++mt)
#pragma unroll
        for (int reg = 0; reg < 4; ++reg) {
          float sv = sc[nt][mt][reg] * SCALE_F;
          e[mt][reg] = sv;
          mx = fmaxf(mx, sv);
        }
      mx = fmaxf(mx, __shfl_xor(mx, 16));
      mx = fmaxf(mx, __shfl_xor(mx, 32));
      float sum = 0.f;
#pragma unroll
      for (int mt = 0; mt < 2; ++mt)
#pragma unroll
        for (int reg = 0; reg < 4; ++reg) {
          e[mt][reg] = __expf(e[mt][reg] - mx);
          sum += e[mt][reg];
        }
      sum += __shfl_xor(sum, 16);
      sum += __shfl_xor(sum, 32);
      float rinv = 1.f / sum;
      float mx2 = -3.4e38f;
#pragma unroll
      for (int mt = 0; mt < 2; ++mt)
#pragma unroll
        for (int reg = 0; reg < 4; ++reg) {
          int j_idx = mt * 16 + g * 4 + reg;
          float t = e[mt][reg] * rinv + rpbs[(i_idx - j_idx + 31) * 16 + h];
          e[mt][reg] = t;
          mx2 = fmaxf(mx2, t);
        }
      mx2 = fmaxf(mx2, __shfl_xor(mx2, 16));
      mx2 = fmaxf(mx2, __shfl_xor(mx2, 32));
      float sum2 = 0.f;
#pragma unroll
      for (int mt = 0; mt < 2; ++mt)
#pragma unroll
        for (int reg = 0; reg < 4; ++reg) {
          float ev = __expf(e[mt][reg] - mx2);
          e[mt][reg] = ev;
          sum2 += ev;
        }
      sum2 += __shfl_xor(sum2, 16);
      sum2 += __shfl_xor(sum2, 32);
      float rinv2 = 1.f / sum2;
#pragma unroll
      for (int mt = 0; mt < 2; ++mt)
#pragma unroll
        for (int reg = 0; reg < 4; ++reg)
          att2[nt][mt][reg] = e[mt][reg] * rinv2;
    }

    // write att[i][j] (packed transposed) into qb (q is dead)
#pragma unroll
    for (int nt = 0; nt < 2; ++nt)
#pragma unroll
      for (int mt = 0; mt < 2; ++mt) {
        u16x4 p = { f2bf(att2[nt][mt][0]), f2bf(att2[nt][mt][1]),
                    f2bf(att2[nt][mt][2]), f2bf(att2[nt][mt][3]) };
        *(u16x4*)(qb + (nt * 16 + l15) * 40 + mt * 16 + g * 4) = p;
      }
    asm volatile("s_waitcnt lgkmcnt(0)" ::: "memory");
    __builtin_amdgcn_sched_barrier(0);

    // ---- PV: ov[nt][mt][reg] = out[i=mt*16+g*4+reg][d=nt*16+l15] ----
    f32x4 ov[2][2];
    {
      s16x8 pa0 = *(const s16x8*)((const char*)qb + l15 * 80 + (g << 4));
      s16x8 pa1 = *(const s16x8*)((const char*)qb + (16 + l15) * 80 + (g << 4));
      s16x8 vf0 = *(const s16x8*)((const char*)vtb + l15 * 80 + (g << 4));
      s16x8 vf1 = *(const s16x8*)((const char*)vtb + (16 + l15) * 80 + (g << 4));
      ov[0][0] = MFMA(pa0, vf0, z4);
      ov[0][1] = MFMA(pa1, vf0, z4);
      ov[1][0] = MFMA(pa0, vf1, z4);
      ov[1][1] = MFMA(pa1, vf1, z4);
    }
    // att_out[n][c = h*32 + nt*16 + l15] -> swizzled abuf
#pragma unroll
    for (int nt = 0; nt < 2; ++nt)
#pragma unroll
      for (int mt = 0; mt < 2; ++mt)
#pragma unroll
        for (int reg = 0; reg < 4; ++reg) {
          int n = mt * 16 + g * 4 + reg;
          int cb = (h * 32 + nt * 16 + l15) << 1;
          *(u16*)((char*)abuf + (((n << 10) + cb) ^ ((n & 7) << 4))) = f2bf(ov[nt][mt][reg]);
        }
  }  // hh
  __syncthreads();

  // ---- final GEMM: out[n][o] = att_out[n][:] . out_w[o][:] + out_b[o] ----
  f32x4 facc[4][2];
#pragma unroll
  for (int t = 0; t < 4; ++t) { facc[t][0] = z4; facc[t][1] = z4; }
  const char* worow[4];
#pragma unroll
  for (int t = 0; t < 4; ++t)
    worow[t] = (const char*)wout +
        (((size_t)((wv * 4 + t) * 16 + l15)) << 10) + (g << 4);

#pragma unroll
  for (int ks = 0; ks < 16; ++ks) {
    s16x8 a0 = *(const s16x8*)((const char*)abuf +
                (((r0 << 10) + (ks << 6) + (g << 4)) ^ ((r0 & 7) << 4)));
    s16x8 a1 = *(const s16x8*)((const char*)abuf +
                (((r1 << 10) + (ks << 6) + (g << 4)) ^ ((r1 & 7) << 4)));
#pragma unroll
    for (int t = 0; t < 4; ++t) {
      s16x8 bf = *(const s16x8*)(worow[t] + (ks << 6));
      facc[t][0] = MFMA(a0, bf, facc[t][0]);
      facc[t][1] = MFMA(a1, bf, facc[t][1]);
    }
  }
  float* og = out + bb * 16384;
#pragma unroll
  for (int t = 0; t < 4; ++t) {
    int ocol = (wv * 4 + t) * 16 + l15;
    float bo = outb[ocol];
#pragma unroll
    for (int reg = 0; reg < 4; ++reg) {
      og[(g * 4 + reg) * 512 + ocol]      = facc[t][0][reg] + bo;
      og[(16 + g * 4 + reg) * 512 + ocol] = facc[t][1][reg] + bo;
    }
  }
}

extern "C" void kernel_launch(void* const* d_in, const int* in_sizes, int n_in,
                              void* d_out, int out_size, void* d_ws, size_t ws_size,
                              hipStream_t stream) {
  const float* x     = (const float*)d_in[0];
  const float* qkv_w = (const float*)d_in[1];
  const float* out_w = (const float*)d_in[2];
  const float* outb  = (const float*)d_in[3];
  const float* rpb   = (const float*)d_in[4];
  float* out = (float*)d_out;

  u16* wq = (u16*)d_ws;            // 1536*512 bf16
  u16* wo = wq + 786432;           // 512*512 bf16   (total ws use: 2 MB)

  cvt_kernel<<<4096, 256, 0, stream>>>(qkv_w, out_w, wq, wo);

  hipFuncSetAttribute((const void*)swa_fused,
                      hipFuncAttributeMaxDynamicSharedMemorySize, SMEM_BYTES);
  swa_fused<<<4096, 512, SMEM_BYTES, stream>>>(x, wq, wo, outb, rpb, out);
}

// Round 3
// 1346.466 us; speedup vs baseline: 1.0761x; 1.0761x over previous
//
#include <hip/hip_runtime.h>

// Problem constants: B=4096, N=32, C=512, H=16, D=32, W=32
#define SCALE_F 0.17677669529663689f  // 32^-0.5

typedef unsigned short u16;
typedef u16  u16x4 __attribute__((ext_vector_type(4)));
typedef short s16x8 __attribute__((ext_vector_type(8)));
typedef float f32x4 __attribute__((ext_vector_type(4)));

#define MFMA(a, b, c) __builtin_amdgcn_mfma_f32_16x16x32_bf16((a), (b), (c), 0, 0, 0)

static __device__ __forceinline__ u16 f2bf(float f) {
  union { float f; unsigned u; } v; v.f = f;
  unsigned r = v.u + 0x7fffu + ((v.u >> 16) & 1u);  // RNE
  return (u16)(r >> 16);
}

// ---- LDS geometry (u16 units) ----
// xbuf : 32x512 bf16 xor-swizzled (reused as att_out staging)  -> 16384 u16
// rpbs : [16][64] f32 (transposed, idx padded 63->64)          ->  4096 B
// per-wave: buf0,buf1 each 32 rows x 40 u16 (80B rows)         ->  2560 u16/wave
#define RPB_OFF_U16   16384
#define WAVE_OFF_U16  18432
#define WBUF_U16      2560
#define SMEM_BYTES    ((WAVE_OFF_U16 + 8 * WBUF_U16) * 2)  // 77824 B -> 2 blocks/CU

__global__ __launch_bounds__(256) void cvt_kernel(const float* __restrict__ qkv_w,
                                                  const float* __restrict__ out_w,
                                                  u16* __restrict__ wq,
                                                  u16* __restrict__ wo) {
  int i = blockIdx.x * 256 + threadIdx.x;
  if (i < 786432) wq[i] = f2bf(qkv_w[i]);
  else            wo[i - 786432] = f2bf(out_w[i - 786432]);
}

__global__ __launch_bounds__(512, 4) void swa_fused(
    const float* __restrict__ x, const u16* __restrict__ wqkv,
    const u16* __restrict__ wout, const float* __restrict__ outb,
    const float* __restrict__ rpb, float* __restrict__ out) {
  extern __shared__ u16 smem[];
  u16* xbuf = smem;
  float* rpbs = (float*)(smem + RPB_OFF_U16);  // [h][idx<64]
  const int tid = threadIdx.x;
  const int lane = tid & 63, wv = tid >> 6;
  const int l15 = lane & 15, g = lane >> 4;
  const long bb = blockIdx.x;
  u16* buf0 = smem + WAVE_OFF_U16 + wv * WBUF_U16;  // q[n][d]; later vT[d][y]
  u16* buf1 = buf0 + 1280;                          // k[j][d]; later att[i][j]

  // ---- stage x[b] -> bf16 swizzled LDS ----
  const f32x4* xg = (const f32x4*)(x + bb * 16384);
#pragma unroll
  for (int it = 0; it < 8; ++it) {
    int f4 = tid + it * 512;
    f32x4 v = xg[f4];
    int r = f4 >> 7, c8 = (f4 & 127) << 3;
    u16x4 p = { f2bf(v.x), f2bf(v.y), f2bf(v.z), f2bf(v.w) };
    *(u16x4*)((char*)xbuf + (((r << 10) + c8) ^ ((r & 7) << 4))) = p;
  }
  // rpb transposed: rpbs[h][idx] = rpb[idx*16+h]; 1008 entries
  for (int it = tid; it < 1008; it += 512)
    rpbs[(it & 15) * 64 + (it >> 4)] = rpb[it];
  __syncthreads();

  const int r0 = l15, r1 = 16 + l15;
  const f32x4 z4 = {0.f, 0.f, 0.f, 0.f};
  u16x4 oreg[2][2][2];  // [hh][nt][mt] packed att-out, written to xbuf later

  for (int hh = 0; hh < 2; ++hh) {
    const int h = wv * 2 + hh;

    // ---- QKV GEMM for head h: 12 interleaved acc chains ----
    f32x4 acc[3][2][2];
#pragma unroll
    for (int m = 0; m < 3; ++m)
#pragma unroll
      for (int nt = 0; nt < 2; ++nt)
#pragma unroll
        for (int mt = 0; mt < 2; ++mt) acc[m][nt][mt] = z4;

    const char* wrow[3][2];
#pragma unroll
    for (int m = 0; m < 3; ++m)
#pragma unroll
      for (int nt = 0; nt < 2; ++nt)
        wrow[m][nt] = (const char*)wqkv +
            (((size_t)(m * 512 + h * 32 + nt * 16 + l15)) << 10) + (g << 4);

#pragma unroll
    for (int ks = 0; ks < 16; ++ks) {
      s16x8 a0 = *(const s16x8*)((const char*)xbuf +
                  (((r0 << 10) + (ks << 6) + (g << 4)) ^ ((r0 & 7) << 4)));
      s16x8 a1 = *(const s16x8*)((const char*)xbuf +
                  (((r1 << 10) + (ks << 6) + (g << 4)) ^ ((r1 & 7) << 4)));
#pragma unroll
      for (int m = 0; m < 3; ++m)
#pragma unroll
        for (int nt = 0; nt < 2; ++nt) {
          s16x8 bf = *(const s16x8*)(wrow[m][nt] + (ks << 6));
          acc[m][nt][0] = MFMA(a0, bf, acc[m][nt][0]);
          acc[m][nt][1] = MFMA(a1, bf, acc[m][nt][1]);
        }
    }

    // epilogue: q -> buf0[n][d], k -> buf1[j][d] (scalar col writes);
    // v packed to regs (written to LDS only after S' frees buf0)
    u16x4 vreg[2][2];
#pragma unroll
    for (int nt = 0; nt < 2; ++nt) {
#pragma unroll
      for (int reg = 0; reg < 4; ++reg) {
        buf0[(g * 4 + reg) * 40 + nt * 16 + l15]      = f2bf(acc[0][nt][0][reg]);
        buf0[(16 + g * 4 + reg) * 40 + nt * 16 + l15] = f2bf(acc[0][nt][1][reg]);
        buf1[(g * 4 + reg) * 40 + nt * 16 + l15]      = f2bf(acc[1][nt][0][reg]);
        buf1[(16 + g * 4 + reg) * 40 + nt * 16 + l15] = f2bf(acc[1][nt][1][reg]);
      }
#pragma unroll
      for (int mt = 0; mt < 2; ++mt) {
        u16x4 p = { f2bf(acc[2][nt][mt][0]), f2bf(acc[2][nt][mt][1]),
                    f2bf(acc[2][nt][mt][2]), f2bf(acc[2][nt][mt][3]) };
        vreg[nt][mt] = p;
      }
    }
    asm volatile("s_waitcnt lgkmcnt(0)" ::: "memory");
    __builtin_amdgcn_sched_barrier(0);

    // ---- S' = K @ Q^T : sc[nt][mt][reg] = S[j=mt*16+g*4+reg][i=nt*16+l15] ----
    f32x4 sc[2][2];
    {
      s16x8 ka0 = *(const s16x8*)((const char*)buf1 + l15 * 80 + (g << 4));
      s16x8 ka1 = *(const s16x8*)((const char*)buf1 + (16 + l15) * 80 + (g << 4));
      s16x8 qf0 = *(const s16x8*)((const char*)buf0 + l15 * 80 + (g << 4));
      s16x8 qf1 = *(const s16x8*)((const char*)buf0 + (16 + l15) * 80 + (g << 4));
      sc[0][0] = MFMA(ka0, qf0, z4);
      sc[0][1] = MFMA(ka1, qf0, z4);
      sc[1][0] = MFMA(ka0, qf1, z4);
      sc[1][1] = MFMA(ka1, qf1, z4);
    }

    // ---- double softmax over j (per column i; fp32) ----
    float att2[2][2][4];
#pragma unroll
    for (int nt = 0; nt < 2; ++nt) {
      const int i_idx = nt * 16 + l15;
      float e[2][4];
      float mx = -3.4e38f;
#pragma unroll
      for (int mt = 0; mt < 2; ++mt)
#pragma unroll
        for (int reg = 0; reg < 4; ++reg) {
          float sv = sc[nt][mt][reg] * SCALE_F;
          e[mt][reg] = sv;
          mx = fmaxf(mx, sv);
        }
      mx = fmaxf(mx, __shfl_xor(mx, 16));
      mx = fmaxf(mx, __shfl_xor(mx, 32));
      float sum = 0.f;
#pragma unroll
      for (int mt = 0; mt < 2; ++mt)
#pragma unroll
        for (int reg = 0; reg < 4; ++reg) {
          e[mt][reg] = __expf(e[mt][reg] - mx);
          sum += e[mt][reg];
        }
      sum += __shfl_xor(sum, 16);
      sum += __shfl_xor(sum, 32);
      float rinv = 1.f / sum;
      float mx2 = -3.4e38f;
#pragma unroll
      for (int mt = 0; mt < 2; ++mt)
#pragma unroll
        for (int reg = 0; reg < 4; ++reg) {
          int j_idx = mt * 16 + g * 4 + reg;
          float t = e[mt][reg] * rinv + rpbs[h * 64 + (i_idx - j_idx + 31)];
          e[mt][reg] = t;
          mx2 = fmaxf(mx2, t);
        }
      mx2 = fmaxf(mx2, __shfl_xor(mx2, 16));
      mx2 = fmaxf(mx2, __shfl_xor(mx2, 32));
      float sum2 = 0.f;
#pragma unroll
      for (int mt = 0; mt < 2; ++mt)
#pragma unroll
        for (int reg = 0; reg < 4; ++reg) {
          float ev = __expf(e[mt][reg] - mx2);
          e[mt][reg] = ev;
          sum2 += ev;
        }
      sum2 += __shfl_xor(sum2, 16);
      sum2 += __shfl_xor(sum2, 32);
      float rinv2 = 1.f / sum2;
#pragma unroll
      for (int mt = 0; mt < 2; ++mt)
#pragma unroll
        for (int reg = 0; reg < 4; ++reg)
          att2[nt][mt][reg] = e[mt][reg] * rinv2;
    }

    // q,k dead: write vT[d][y] -> buf0, att[i][j] -> buf1
    __builtin_amdgcn_sched_barrier(0);
#pragma unroll
    for (int nt = 0; nt < 2; ++nt)
#pragma unroll
      for (int mt = 0; mt < 2; ++mt) {
        *(u16x4*)(buf0 + (nt * 16 + l15) * 40 + mt * 16 + g * 4) = vreg[nt][mt];
        u16x4 p = { f2bf(att2[nt][mt][0]), f2bf(att2[nt][mt][1]),
                    f2bf(att2[nt][mt][2]), f2bf(att2[nt][mt][3]) };
        *(u16x4*)(buf1 + (nt * 16 + l15) * 40 + mt * 16 + g * 4) = p;
      }
    asm volatile("s_waitcnt lgkmcnt(0)" ::: "memory");
    __builtin_amdgcn_sched_barrier(0);

    // ---- PV: ov[nt][mt][reg] = out[i=mt*16+g*4+reg][d=nt*16+l15] ----
    f32x4 ov[2][2];
    {
      s16x8 pa0 = *(const s16x8*)((const char*)buf1 + l15 * 80 + (g << 4));
      s16x8 pa1 = *(const s16x8*)((const char*)buf1 + (16 + l15) * 80 + (g << 4));
      s16x8 vf0 = *(const s16x8*)((const char*)buf0 + l15 * 80 + (g << 4));
      s16x8 vf1 = *(const s16x8*)((const char*)buf0 + (16 + l15) * 80 + (g << 4));
      ov[0][0] = MFMA(pa0, vf0, z4);
      ov[0][1] = MFMA(pa1, vf0, z4);
      ov[1][0] = MFMA(pa0, vf1, z4);
      ov[1][1] = MFMA(pa1, vf1, z4);
    }
#pragma unroll
    for (int nt = 0; nt < 2; ++nt)
#pragma unroll
      for (int mt = 0; mt < 2; ++mt) {
        u16x4 p = { f2bf(ov[nt][mt][0]), f2bf(ov[nt][mt][1]),
                    f2bf(ov[nt][mt][2]), f2bf(ov[nt][mt][3]) };
        oreg[hh][nt][mt] = p;
      }
  }  // hh
  __syncthreads();  // all waves done reading xbuf (QKV) -> reuse as att_out

  // scatter att_out[n][c = h*32 + nt*16 + l15] -> swizzled xbuf
#pragma unroll
  for (int hh = 0; hh < 2; ++hh)
#pragma unroll
    for (int nt = 0; nt < 2; ++nt)
#pragma unroll
      for (int mt = 0; mt < 2; ++mt)
#pragma unroll
        for (int reg = 0; reg < 4; ++reg) {
          int n = mt * 16 + g * 4 + reg;
          int cb = ((wv * 2 + hh) * 32 + nt * 16 + l15) << 1;
          *(u16*)((char*)xbuf + (((n << 10) + cb) ^ ((n & 7) << 4))) =
              oreg[hh][nt][mt][reg];
        }
  __syncthreads();

  // ---- final GEMM: out[n][o] = att_out[n][:] . out_w[o][:] + out_b[o] ----
  f32x4 facc[4][2];
#pragma unroll
  for (int t = 0; t < 4; ++t) { facc[t][0] = z4; facc[t][1] = z4; }
  const char* worow[4];
#pragma unroll
  for (int t = 0; t < 4; ++t)
    worow[t] = (const char*)wout +
        (((size_t)((wv * 4 + t) * 16 + l15)) << 10) + (g << 4);

#pragma unroll
  for (int ks = 0; ks < 16; ++ks) {
    s16x8 a0 = *(const s16x8*)((const char*)xbuf +
                (((r0 << 10) + (ks << 6) + (g << 4)) ^ ((r0 & 7) << 4)));
    s16x8 a1 = *(const s16x8*)((const char*)xbuf +
                (((r1 << 10) + (ks << 6) + (g << 4)) ^ ((r1 & 7) << 4)));
#pragma unroll
    for (int t = 0; t < 4; ++t) {
      s16x8 bf = *(const s16x8*)(worow[t] + (ks << 6));
      facc[t][0] = MFMA(a0, bf, facc[t][0]);
      facc[t][1] = MFMA(a1, bf, facc[t][1]);
    }
  }
  float* og = out + bb * 16384;
#pragma unroll
  for (int t = 0; t < 4; ++t) {
    int ocol = (wv * 4 + t) * 16 + l15;
    float bo = outb[ocol];
#pragma unroll
    for (int reg = 0; reg < 4; ++reg) {
      og[(g * 4 + reg) * 512 + ocol]      = facc[t][0][reg] + bo;
      og[(16 + g * 4 + reg) * 512 + ocol] = facc[t][1][reg] + bo;
    }
  }
}

extern "C" void kernel_launch(void* const* d_in, const int* in_sizes, int n_in,
                              void* d_out, int out_size, void* d_ws, size_t ws_size,
                              hipStream_t stream) {
  const float* x     = (const float*)d_in[0];
  const float* qkv_w = (const float*)d_in[1];
  const float* out_w = (const float*)d_in[2];
  const float* outb  = (const float*)d_in[3];
  const float* rpb   = (const float*)d_in[4];
  float* out = (float*)d_out;

  u16* wq = (u16*)d_ws;            // 1536*512 bf16
  u16* wo = wq + 786432;           // 512*512 bf16

  cvt_kernel<<<4096, 256, 0, stream>>>(qkv_w, out_w, wq, wo);

  hipFuncSetAttribute((const void*)swa_fused,
                      hipFuncAttributeMaxDynamicSharedMemorySize, SMEM_BYTES);
  swa_fused<<<4096, 512, SMEM_BYTES, stream>>>(x, wq, wo, outb, rpb, out);
}